// Round 1
// baseline (656.785 us; speedup 1.0000x reference)
//
#include <hip/hip_runtime.h>
#include <cstdint>
#include <cstddef>

#define NB 32
#define NL 2880
#define NC_TOT 862
#define NPRED 720
#define NSEG 48
#define NMAP 4
#define NK 16
#define NIN 60
#define NOUT 15
#define NCONV 359

// ---------------------------------------------------------------------------
// Kernel 1: per-(b,c) stats + gates in ONE pass over x.
// block 256 = 32 channels x 8 L-chunks (chunk = 360 l-values = 45 conv outputs)
// grid (ceil(862/32)=27, 32)
// ---------------------------------------------------------------------------
__global__ __launch_bounds__(256) void k1_stats_gates(
    const float* __restrict__ x,
    const float* __restrict__ conv_w,
    const float* __restrict__ conv_b,
    const float* __restrict__ gate_w,
    const float* __restrict__ gate_b,
    float* __restrict__ ws2)
{
  __shared__ __align__(16) float gw[NCONV * 4];   // [d][m]
  __shared__ float red[6][8][32];
  __shared__ float g1s[4];

  const int tid = threadIdx.x;

  // stage gate_w transposed -> [d][m]
  for (int idx = tid; idx < NMAP * NCONV; idx += 256) {
    int m = idx / NCONV;
    int d = idx - m * NCONV;
    gw[d * 4 + m] = gate_w[idx];
  }
  __syncthreads();

  // wave 0 computes G1[m] = sum_d gate_w[m,d]
  if (tid < 64) {
    float p0 = 0.f, p1 = 0.f, p2 = 0.f, p3 = 0.f;
    for (int d = tid; d < NCONV; d += 64) {
      p0 += gw[d * 4 + 0];
      p1 += gw[d * 4 + 1];
      p2 += gw[d * 4 + 2];
      p3 += gw[d * 4 + 3];
    }
    #pragma unroll
    for (int off = 32; off > 0; off >>= 1) {
      p0 += __shfl_down(p0, off, 64);
      p1 += __shfl_down(p1, off, 64);
      p2 += __shfl_down(p2, off, 64);
      p3 += __shfl_down(p3, off, 64);
    }
    if (tid == 0) { g1s[0] = p0; g1s[1] = p1; g1s[2] = p2; g1s[3] = p3; }
  }

  const int cl = tid & 31;
  const int q  = tid >> 5;                // 0..7
  const int c  = blockIdx.x * 32 + cl;
  const int b  = blockIdx.y;
  const bool active = (c < NC_TOT);

  float sum = 0.f, sumsq = 0.f;
  float gacc0 = 0.f, gacc1 = 0.f, gacc2 = 0.f, gacc3 = 0.f;
  float Sw = 0.f;

  if (active) {
    const float* xp = x + (size_t)b * NL * NC_TOT + c;
    float w[NK];
    #pragma unroll
    for (int k = 0; k < NK; ++k) { w[k] = conv_w[c * NK + k]; Sw += w[k]; }

    float A[8], Bv[8];
    const int d0 = q * 45;
    const int d1 = (q == 7) ? NCONV : (d0 + 45);
    const int dlast = q * 45 + 44;        // its loads belong to next chunk's stats (q<7)

    #pragma unroll
    for (int j = 0; j < 8; ++j) {
      float v = xp[(size_t)(d0 * 8 + j) * NC_TOT];
      A[j] = v; sum += v; sumsq = fmaf(v, v, sumsq);
    }
    for (int d = d0; d < d1; ++d) {
      #pragma unroll
      for (int j = 0; j < 8; ++j)
        Bv[j] = xp[(size_t)(d * 8 + 8 + j) * NC_TOT];
      if (d != dlast) {
        #pragma unroll
        for (int j = 0; j < 8; ++j) { sum += Bv[j]; sumsq = fmaf(Bv[j], Bv[j], sumsq); }
      }
      float cr = 0.f;
      #pragma unroll
      for (int j = 0; j < 8; ++j) cr = fmaf(A[j], w[j], cr);
      #pragma unroll
      for (int j = 0; j < 8; ++j) cr = fmaf(Bv[j], w[j + 8], cr);
      const float4 g4 = *(const float4*)&gw[d * 4];
      gacc0 = fmaf(cr, g4.x, gacc0);
      gacc1 = fmaf(cr, g4.y, gacc1);
      gacc2 = fmaf(cr, g4.z, gacc2);
      gacc3 = fmaf(cr, g4.w, gacc3);
      #pragma unroll
      for (int j = 0; j < 8; ++j) A[j] = Bv[j];
    }
  }

  red[0][q][cl] = sum;
  red[1][q][cl] = sumsq;
  red[2][q][cl] = gacc0;
  red[3][q][cl] = gacc1;
  red[4][q][cl] = gacc2;
  red[5][q][cl] = gacc3;
  __syncthreads();

  if (tid < 32 && active) {
    float t[6];
    #pragma unroll
    for (int cc = 0; cc < 6; ++cc) {
      float s = 0.f;
      #pragma unroll
      for (int qq = 0; qq < 8; ++qq) s += red[cc][qq][tid];
      t[cc] = s;
    }
    const float mean = t[0] * (1.0f / NL);
    const float var  = t[1] * (1.0f / NL) - mean * mean;
    const float sd   = sqrtf(var + 1e-10f);
    const float rstd = 1.0f / sd;
    const float cb   = conv_b[c];
    const float k0   = cb - rstd * mean * Sw;
    float lg[4];
    lg[0] = rstd * t[2] + k0 * g1s[0] + gate_b[0];
    lg[1] = rstd * t[3] + k0 * g1s[1] + gate_b[1];
    lg[2] = rstd * t[4] + k0 * g1s[2] + gate_b[2];
    lg[3] = rstd * t[5] + k0 * g1s[3] + gate_b[3];
    const float mx = fmaxf(fmaxf(lg[0], lg[1]), fmaxf(lg[2], lg[3]));
    const float e0 = expf(lg[0] - mx);
    const float e1 = expf(lg[1] - mx);
    const float e2 = expf(lg[2] - mx);
    const float e3 = expf(lg[3] - mx);
    const float inv = 1.0f / (e0 + e1 + e2 + e3);

    const size_t cs = (size_t)NB * NC_TOT;
    float* o2 = ws2 + (size_t)b * NC_TOT + c;
    o2[0 * cs] = mean;
    o2[1 * cs] = sd;
    o2[2 * cs] = e0 * inv;
    o2[3 * cs] = e1 * inv;
    o2[4 * cs] = e2 * inv;
    o2[5 * cs] = e3 * inv;
  }
}

// ---------------------------------------------------------------------------
// Kernel 2: gated mixture output.
// block 384 = 16 channels x 24 s-groups (each thread: s and s+24 fused)
// grid (ceil(862/16)=54, 32)
// ---------------------------------------------------------------------------
__global__ __launch_bounds__(384) void k2_out(
    const float* __restrict__ x,
    const float* __restrict__ map_w,
    const float* __restrict__ map_b,
    const float* __restrict__ ws2,
    float* __restrict__ out)
{
  __shared__ __align__(16) float weff[16 * 900];   // [cl][o*60+i], stride 900: aligned, 2-way bank alias (free)
  __shared__ float sgl[6][16];                     // mean, sd, g0..g3 per channel
  __shared__ float beff[16 * 16];                  // [cl][o]

  const int tid = threadIdx.x;
  const int b  = blockIdx.y;
  const int c0 = blockIdx.x * 16;
  const size_t cs = (size_t)NB * NC_TOT;

  if (tid < 6 * 16) {
    int comp = tid >> 4;
    int cl   = tid & 15;
    int cc   = c0 + cl;
    if (cc > NC_TOT - 1) cc = NC_TOT - 1;          // clamp: stay in-bounds, masked later
    sgl[comp][cl] = ws2[comp * cs + (size_t)b * NC_TOT + cc];
  }
  __syncthreads();

  // stage W_eff[cl][o,i] = sum_m g_m * map_w[m,o,i]
  for (int idx = tid; idx < 16 * 900; idx += 384) {
    int cl = idx / 900;
    int oi = idx - cl * 900;
    weff[idx] = sgl[2][cl] * map_w[oi]
              + sgl[3][cl] * map_w[900  + oi]
              + sgl[4][cl] * map_w[1800 + oi]
              + sgl[5][cl] * map_w[2700 + oi];
  }
  if (tid < 16 * NOUT) {
    int cl = tid / NOUT;
    int o  = tid - cl * NOUT;
    beff[cl * 16 + o] = sgl[2][cl] * map_b[o]
                      + sgl[3][cl] * map_b[15 + o]
                      + sgl[4][cl] * map_b[30 + o]
                      + sgl[5][cl] * map_b[45 + o];
  }
  __syncthreads();

  const int cl = tid & 15;
  const int sg = tid >> 4;              // 0..23  -> handles s=sg and s=sg+24
  const int c  = c0 + cl;
  const bool active = (c < NC_TOT);
  const float mean = sgl[0][cl];
  const float sd   = sgl[1][cl];

  float xa[NIN], xb[NIN];
  const float* xp = x + (size_t)b * NL * NC_TOT + c;
  if (active) {
    #pragma unroll
    for (int i = 0; i < NIN; ++i) {
      xa[i] = xp[(size_t)(i * 48 + sg) * NC_TOT] - mean;
      xb[i] = xp[(size_t)(i * 48 + sg + 24) * NC_TOT] - mean;
    }
  } else {
    #pragma unroll
    for (int i = 0; i < NIN; ++i) { xa[i] = 0.f; xb[i] = 0.f; }
  }

  float* op = out + (size_t)b * NPRED * NC_TOT + c;
  const float* wrow = &weff[cl * 900];
  for (int o = 0; o < NOUT; ++o) {
    float aa = 0.f, ab = 0.f;
    #pragma unroll
    for (int i4 = 0; i4 < 15; ++i4) {
      const float4 w4 = *(const float4*)&wrow[o * 60 + i4 * 4];
      aa = fmaf(xa[i4 * 4 + 0], w4.x, aa);
      aa = fmaf(xa[i4 * 4 + 1], w4.y, aa);
      aa = fmaf(xa[i4 * 4 + 2], w4.z, aa);
      aa = fmaf(xa[i4 * 4 + 3], w4.w, aa);
      ab = fmaf(xb[i4 * 4 + 0], w4.x, ab);
      ab = fmaf(xb[i4 * 4 + 1], w4.y, ab);
      ab = fmaf(xb[i4 * 4 + 2], w4.z, ab);
      ab = fmaf(xb[i4 * 4 + 3], w4.w, ab);
    }
    const float cst = fmaf(sd, beff[cl * 16 + o], mean);
    if (active) {
      op[(size_t)(o * 48 + sg) * NC_TOT]      = aa + cst;
      op[(size_t)(o * 48 + sg + 24) * NC_TOT] = ab + cst;
    }
  }
}

// ---------------------------------------------------------------------------
extern "C" void kernel_launch(void* const* d_in, const int* in_sizes, int n_in,
                              void* d_out, int out_size, void* d_ws, size_t ws_size,
                              hipStream_t stream)
{
  (void)in_sizes; (void)n_in; (void)out_size; (void)ws_size;
  const float* x      = (const float*)d_in[0];
  const float* conv_w = (const float*)d_in[1];
  const float* conv_b = (const float*)d_in[2];
  const float* gate_w = (const float*)d_in[3];
  const float* gate_b = (const float*)d_in[4];
  const float* map_w  = (const float*)d_in[5];
  const float* map_b  = (const float*)d_in[6];
  float* out = (float*)d_out;
  float* ws2 = (float*)d_ws;    // 6 * 32 * 862 floats = 662 KB

  dim3 g1((NC_TOT + 31) / 32, NB), b1(256);
  hipLaunchKernelGGL(k1_stats_gates, g1, b1, 0, stream,
                     x, conv_w, conv_b, gate_w, gate_b, ws2);

  dim3 g2((NC_TOT + 15) / 16, NB), b2(384);
  hipLaunchKernelGGL(k2_out, g2, b2, 0, stream,
                     x, map_w, map_b, ws2, out);
}